// Round 2
// baseline (578.155 us; speedup 1.0000x reference)
//
#include <hip/hip_runtime.h>
#include <math.h>

#define NIMG 8
#define CIN 8
#define Hh 136
#define Ww 200
#define HW (Hh * Ww)
#define OH 272
#define OW 400
#define NINST 512
#define NPAR 169
#define TROWS 34
#define NTILES 8
#define LROWS 19

__global__ __launch_bounds__(256, 2) void dmh_main(
    const float* __restrict__ feats,
    const float* __restrict__ pars,
    const float* __restrict__ iloc,
    const float* __restrict__ gt,
    const int* __restrict__ iminds,
    const int* __restrict__ lvls,
    float* __restrict__ acc)
{
    __shared__ float slog[LROWS * Ww];
    __shared__ float sred[12];

    const int n    = blockIdx.y;
    const int tile = blockIdx.x;
    const int tid  = threadIdx.x;

    const float ix = iloc[2 * n + 0];
    const float iy = iloc[2 * n + 1];
    const int   im = iminds[n];
    const float invsoi = 1.0f / (float)(64 << lvls[n]);

    // ---- per-instance params -> registers (kept live: __launch_bounds__(256,2)) ----
    const float* pp = pars + n * NPAR;
    float Wf[64], w1[64], w2[8], b1[8], A0[8], Ax[8], Ay[8], b2;
#pragma unroll
    for (int o = 0; o < 8; o++) {
        const float wx0 = pp[o * 10 + 0];
        const float wy0 = pp[o * 10 + 1];
        Ax[o] = -8.0f * invsoi * wx0;
        Ay[o] = -8.0f * invsoi * wy0;
        A0[o] = pp[152 + o] + wx0 * (ix - 4.0f) * invsoi + wy0 * (iy - 4.0f) * invsoi;
#pragma unroll
        for (int c = 0; c < 8; c++) Wf[o * 8 + c] = pp[o * 10 + 2 + c];
    }
#pragma unroll
    for (int i = 0; i < 64; i++) w1[i] = pp[80 + i];
#pragma unroll
    for (int i = 0; i < 8; i++)  w2[i] = pp[144 + i];
#pragma unroll
    for (int i = 0; i < 8; i++)  b1[i] = pp[160 + i];
    b2 = pp[168];

    const float sy = 135.0f / 271.0f;
    const float sx = 199.0f / 399.0f;

    const int oy0 = tile * TROWS;
    const int ly0 = (int)((float)oy0 * sy);
    int lyL = (int)((float)(oy0 + TROWS - 1) * sy) + 1;
    if (lyL > Hh - 1) lyL = Hh - 1;
    const int lycnt = lyL - ly0 + 1;

    // ---- Phase A: low-res logits, 4 px per thread-iteration ----
    const float* fb0 = feats + (size_t)im * (CIN * HW);
    const int nquad = lycnt * (Ww / 4);
    for (int q = tid; q < nquad; q += 256) {
        const int yy = q / 50;
        const int xq = (q - yy * 50) * 4;
        const int y  = ly0 + yy;
        const float yf = (float)y;
        const float* fb = fb0 + y * Ww + xq;
        float f[8][4];
#pragma unroll
        for (int c = 0; c < 8; c++) {
            const float4 t = *reinterpret_cast<const float4*>(fb + c * HW);
            f[c][0] = t.x; f[c][1] = t.y; f[c][2] = t.z; f[c][3] = t.w;
        }
        float pre[8];
#pragma unroll
        for (int o = 0; o < 8; o++) pre[o] = A0[o] + Ay[o] * yf;

        float out4[4];
#pragma unroll
        for (int p = 0; p < 4; p++) {
            const float xf = (float)(xq + p);
            float h[8];
#pragma unroll
            for (int o = 0; o < 8; o++) {
                float a = pre[o] + Ax[o] * xf;
#pragma unroll
                for (int c = 0; c < 8; c++) a += Wf[o * 8 + c] * f[c][p];
                h[o] = fmaxf(a, 0.0f);
            }
            float g[8];
#pragma unroll
            for (int o = 0; o < 8; o++) {
                float a = b1[o];
#pragma unroll
                for (int c = 0; c < 8; c++) a += w1[o * 8 + c] * h[c];
                g[o] = fmaxf(a, 0.0f);
            }
            float lg = b2;
#pragma unroll
            for (int c = 0; c < 8; c++) lg += w2[c] * g[c];
            out4[p] = lg;
        }
        *reinterpret_cast<float4*>(&slog[yy * Ww + xq]) =
            make_float4(out4[0], out4[1], out4[2], out4[3]);
    }
    __syncthreads();

    // ---- Phase B: bilinear up + sigmoid + dice partials, 2 px per iteration ----
    float aI = 0.0f, aS = 0.0f, aT = 0.0f;
    const float* gtn = gt + (size_t)n * (OH * OW) + (size_t)oy0 * OW;
    for (int g2 = tid; g2 < TROWS * (OW / 2); g2 += 256) {
        const int ry = g2 / 200;
        const int gx = (g2 - ry * 200) * 2;
        const int oy = oy0 + ry;
        const float ysf = (float)oy * sy;
        int y0 = (int)ysf;
        const float wy = ysf - (float)y0;
        int y1 = (y0 + 1 > Hh - 1) ? (Hh - 1) : (y0 + 1);
        int r0i = y0 - ly0, r1i = y1 - ly0;
        r0i = r0i < 0 ? 0 : (r0i > lycnt - 1 ? lycnt - 1 : r0i);
        r1i = r1i < 0 ? 0 : (r1i > lycnt - 1 ? lycnt - 1 : r1i);
        const float* s0 = &slog[r0i * Ww];
        const float* s1 = &slog[r1i * Ww];

        const float2 t2 = *reinterpret_cast<const float2*>(gtn + ry * OW + gx);
        const float tval[2] = { t2.x, t2.y };
#pragma unroll
        for (int p = 0; p < 2; p++) {
            const int ox = gx + p;
            const float xsf = (float)ox * sx;
            const int x0 = (int)xsf;
            const float wx = xsf - (float)x0;
            const int x1 = (x0 + 1 > Ww - 1) ? (Ww - 1) : (x0 + 1);
            const float v00 = s0[x0];
            const float v01 = s0[x1];
            const float v10 = s1[x0];
            const float v11 = s1[x1];
            const float top = v00 + wx * (v01 - v00);
            const float bot = v10 + wx * (v11 - v10);
            const float v   = top + wy * (bot - top);
            const float s   = __fdividef(1.0f, 1.0f + __expf(-v));
            aI += s * tval[p];
            aS += s * s;
            aT += tval[p];
        }
    }

    // ---- block reduction ----
#pragma unroll
    for (int off = 32; off > 0; off >>= 1) {
        aI += __shfl_down(aI, off, 64);
        aS += __shfl_down(aS, off, 64);
        aT += __shfl_down(aT, off, 64);
    }
    const int wv = tid >> 6;
    if ((tid & 63) == 0) {
        sred[wv * 3 + 0] = aI;
        sred[wv * 3 + 1] = aS;
        sred[wv * 3 + 2] = aT;
    }
    __syncthreads();
    if (tid == 0) {
        const float I = sred[0] + sred[3] + sred[6] + sred[9];
        const float S = sred[1] + sred[4] + sred[7] + sred[10];
        const float T = sred[2] + sred[5] + sred[8] + sred[11];
        atomicAdd(&acc[n * 3 + 0], I);
        atomicAdd(&acc[n * 3 + 1], S);
        atomicAdd(&acc[n * 3 + 2], T);
    }
}

__global__ __launch_bounds__(256) void dmh_fin(const float* __restrict__ acc,
                                               float* __restrict__ out)
{
    const int i = blockIdx.x * 256 + threadIdx.x;
    if (i < NINST) {
        const float I = acc[i * 3 + 0];
        const float S = acc[i * 3 + 1];
        const float T = acc[i * 3 + 2];
        out[i] = 1.0f - 2.0f * I / (S + T + 1e-5f);
    }
}

extern "C" void kernel_launch(void* const* d_in, const int* in_sizes, int n_in,
                              void* d_out, int out_size, void* d_ws, size_t ws_size,
                              hipStream_t stream) {
    const float* feats  = (const float*)d_in[0];
    const float* pars   = (const float*)d_in[1];
    const float* iloc   = (const float*)d_in[2];
    const float* gt     = (const float*)d_in[3];
    const int*   iminds = (const int*)d_in[4];
    const int*   lvls   = (const int*)d_in[5];
    float* acc = (float*)d_ws;

    hipMemsetAsync(acc, 0, NINST * 3 * sizeof(float), stream);
    dim3 grid(NTILES, NINST);
    dmh_main<<<grid, 256, 0, stream>>>(feats, pars, iloc, gt, iminds, lvls, acc);
    dmh_fin<<<(NINST + 255) / 256, 256, 0, stream>>>(acc, (float*)d_out);
}

// Round 3
// 482.024 us; speedup vs baseline: 1.1994x; 1.1994x over previous
//
#include <hip/hip_runtime.h>
#include <math.h>

#define NIMG 8
#define CIN 8
#define Hh 136
#define Ww 200
#define HW (Hh * Ww)
#define OH 272
#define OW 400
#define NINST 512
#define NPAR 169
#define TROWS 34
#define NTILES 8
#define LROWS 19
#define ACHUNKS 16
#define PAIRS_PER_CHUNK (HW / 2 / ACHUNKS)
#define LOG_OFF_FLOATS 16384
#define WS_NEEDED ((size_t)(LOG_OFF_FLOATS + (size_t)NINST * HW) * 4)

// ---------------- Phase A: per-instance MLP -> logits (global scratch) ----------------
__global__ __launch_bounds__(256, 1) void dmh_mlp(
    const float* __restrict__ feats,
    const float* __restrict__ pars,
    const float* __restrict__ iloc,
    const int* __restrict__ iminds,
    const int* __restrict__ lvls,
    float* __restrict__ logits)
{
    const int n     = blockIdx.y;
    const int chunk = blockIdx.x;
    const int tid   = threadIdx.x;

    const float ix = iloc[2 * n + 0];
    const float iy = iloc[2 * n + 1];
    const int   im = iminds[n];
    const float invsoi = 1.0f / (float)(64 << lvls[n]);

    // 169 per-instance params -> registers. __launch_bounds__(256,1) => 512-VGPR budget.
    const float* pp = pars + n * NPAR;
    float Wf[64], w1[64], w2[8], b1[8], A0[8], Ax[8], Ay[8], b2;
#pragma unroll
    for (int o = 0; o < 8; o++) {
        const float wx0 = pp[o * 10 + 0];
        const float wy0 = pp[o * 10 + 1];
        Ax[o] = -8.0f * invsoi * wx0;
        Ay[o] = -8.0f * invsoi * wy0;
        A0[o] = pp[152 + o] + (wx0 * (ix - 4.0f) + wy0 * (iy - 4.0f)) * invsoi;
#pragma unroll
        for (int c = 0; c < 8; c++) Wf[o * 8 + c] = pp[o * 10 + 2 + c];
    }
#pragma unroll
    for (int i = 0; i < 64; i++) w1[i] = pp[80 + i];
#pragma unroll
    for (int i = 0; i < 8; i++)  w2[i] = pp[144 + i];
#pragma unroll
    for (int i = 0; i < 8; i++)  b1[i] = pp[160 + i];
    b2 = pp[168];

    const float* fb0 = feats + (size_t)im * (CIN * HW);
    float* lgn = logits + (size_t)n * HW;

    const int base = chunk * PAIRS_PER_CHUNK;
    const int end  = base + PAIRS_PER_CHUNK;
    for (int pr = base + tid; pr < end; pr += 256) {
        const int yy = pr / 100;
        const int xp = (pr - yy * 100) * 2;
        const float yf = (float)yy;
        const float* fb = fb0 + yy * Ww + xp;
        float f[8][2];
#pragma unroll
        for (int c = 0; c < 8; c++) {
            const float2 t = *reinterpret_cast<const float2*>(fb + c * HW);
            f[c][0] = t.x; f[c][1] = t.y;
        }
        float pre[8];
#pragma unroll
        for (int o = 0; o < 8; o++) pre[o] = A0[o] + Ay[o] * yf;

        float o2[2];
#pragma unroll
        for (int p = 0; p < 2; p++) {
            const float xf = (float)(xp + p);
            float h[8];
#pragma unroll
            for (int o = 0; o < 8; o++) {
                float a = pre[o] + Ax[o] * xf;
#pragma unroll
                for (int c = 0; c < 8; c++) a += Wf[o * 8 + c] * f[c][p];
                h[o] = fmaxf(a, 0.0f);
            }
            float g[8];
#pragma unroll
            for (int o = 0; o < 8; o++) {
                float a = b1[o];
#pragma unroll
                for (int c = 0; c < 8; c++) a += w1[o * 8 + c] * h[c];
                g[o] = fmaxf(a, 0.0f);
            }
            float lg = b2;
#pragma unroll
            for (int c = 0; c < 8; c++) lg += w2[c] * g[c];
            o2[p] = lg;
        }
        *reinterpret_cast<float2*>(lgn + yy * Ww + xp) = make_float2(o2[0], o2[1]);
    }
}

// ---------------- Phase B: bilinear up + sigmoid + dice partials ----------------
__global__ __launch_bounds__(256) void dmh_dice(
    const float* __restrict__ logits,
    const float* __restrict__ gt,
    float* __restrict__ part)
{
    __shared__ float slog[LROWS * Ww];
    __shared__ float sred[12];

    const int n    = blockIdx.y;
    const int tile = blockIdx.x;
    const int tid  = threadIdx.x;

    const float sy = 135.0f / 271.0f;
    const float sx = 199.0f / 399.0f;

    const int oy0 = tile * TROWS;
    const int ly0 = (int)((float)oy0 * sy);
    int lyL = (int)((float)(oy0 + TROWS - 1) * sy) + 1;
    if (lyL > Hh - 1) lyL = Hh - 1;
    const int lycnt = lyL - ly0 + 1;

    // stage needed logit rows -> LDS (coalesced float4)
    const float* lg = logits + (size_t)n * HW + ly0 * Ww;
    const int nfl = lycnt * Ww;
    for (int i = 4 * tid; i < nfl; i += 1024) {
        *reinterpret_cast<float4*>(&slog[i]) = *reinterpret_cast<const float4*>(lg + i);
    }
    __syncthreads();

    float aI = 0.0f, aS = 0.0f, aT = 0.0f;
    const float* gtn = gt + (size_t)n * (OH * OW) + (size_t)oy0 * OW;
    for (int g4 = tid; g4 < TROWS * (OW / 4); g4 += 256) {
        const int ry = g4 / 100;
        const int gx = (g4 - ry * 100) * 4;
        const int oy = oy0 + ry;
        const float ysf = (float)oy * sy;
        const int y0 = (int)ysf;
        const float wy = ysf - (float)y0;
        const int y1 = (y0 + 1 > Hh - 1) ? (Hh - 1) : (y0 + 1);
        int r0i = y0 - ly0, r1i = y1 - ly0;
        r0i = r0i < 0 ? 0 : (r0i > lycnt - 1 ? lycnt - 1 : r0i);
        r1i = r1i < 0 ? 0 : (r1i > lycnt - 1 ? lycnt - 1 : r1i);
        const float* s0 = &slog[r0i * Ww];
        const float* s1 = &slog[r1i * Ww];

        const float4 t4 = *reinterpret_cast<const float4*>(gtn + ry * OW + gx);
        const float tv[4] = { t4.x, t4.y, t4.z, t4.w };
#pragma unroll
        for (int p = 0; p < 4; p++) {
            const int ox = gx + p;
            const float xsf = (float)ox * sx;
            const int x0 = (int)xsf;
            const float wx = xsf - (float)x0;
            const int x1 = (x0 + 1 > Ww - 1) ? (Ww - 1) : (x0 + 1);
            const float v00 = s0[x0];
            const float v01 = s0[x1];
            const float v10 = s1[x0];
            const float v11 = s1[x1];
            const float top = v00 + wx * (v01 - v00);
            const float bot = v10 + wx * (v11 - v10);
            const float v   = top + wy * (bot - top);
            const float s   = __fdividef(1.0f, 1.0f + __expf(-v));
            aI += s * tv[p];
            aS += s * s;
            aT += tv[p];
        }
    }

#pragma unroll
    for (int off = 32; off > 0; off >>= 1) {
        aI += __shfl_down(aI, off, 64);
        aS += __shfl_down(aS, off, 64);
        aT += __shfl_down(aT, off, 64);
    }
    const int wv = tid >> 6;
    if ((tid & 63) == 0) {
        sred[wv * 3 + 0] = aI;
        sred[wv * 3 + 1] = aS;
        sred[wv * 3 + 2] = aT;
    }
    __syncthreads();
    if (tid == 0) {
        float* pt = part + (size_t)(n * NTILES + tile) * 3;
        pt[0] = sred[0] + sred[3] + sred[6] + sred[9];
        pt[1] = sred[1] + sred[4] + sred[7] + sred[10];
        pt[2] = sred[2] + sred[5] + sred[8] + sred[11];
    }
}

__global__ __launch_bounds__(256) void dmh_fin2(const float* __restrict__ part,
                                                float* __restrict__ out)
{
    const int i = blockIdx.x * 256 + threadIdx.x;
    if (i < NINST) {
        float I = 0.0f, S = 0.0f, T = 0.0f;
#pragma unroll
        for (int t = 0; t < NTILES; t++) {
            const float* pt = part + (size_t)(i * NTILES + t) * 3;
            I += pt[0]; S += pt[1]; T += pt[2];
        }
        out[i] = 1.0f - 2.0f * I / (S + T + 1e-5f);
    }
}

// ---------------- Fallback fused path (R1, known-good) if ws too small ----------------
__global__ __launch_bounds__(256) void dmh_fused(
    const float* __restrict__ feats,
    const float* __restrict__ pars,
    const float* __restrict__ iloc,
    const float* __restrict__ gt,
    const int* __restrict__ iminds,
    const int* __restrict__ lvls,
    float* __restrict__ acc)
{
    __shared__ float slog[LROWS * Ww];
    __shared__ float sred[12];
    const int n = blockIdx.y, tile = blockIdx.x, tid = threadIdx.x;
    const float* pp = pars + n * NPAR;
    float w0[80], w1[64], w2[8], b0[8], b1[8], b2;
#pragma unroll
    for (int i = 0; i < 80; i++) w0[i] = pp[i];
#pragma unroll
    for (int i = 0; i < 64; i++) w1[i] = pp[80 + i];
#pragma unroll
    for (int i = 0; i < 8; i++)  w2[i] = pp[144 + i];
#pragma unroll
    for (int i = 0; i < 8; i++)  b0[i] = pp[152 + i];
#pragma unroll
    for (int i = 0; i < 8; i++)  b1[i] = pp[160 + i];
    b2 = pp[168];
    const float ix = iloc[2 * n + 0], iy = iloc[2 * n + 1];
    const int im = iminds[n];
    const float invsoi = 1.0f / (float)(64 << lvls[n]);
    const float sy = 135.0f / 271.0f, sx = 199.0f / 399.0f;
    const int oy0 = tile * TROWS;
    const int ly0 = (int)((float)oy0 * sy);
    int lyL = (int)((float)(oy0 + TROWS - 1) * sy) + 1;
    if (lyL > Hh - 1) lyL = Hh - 1;
    const int lycnt = lyL - ly0 + 1;
    const float* fb0 = feats + (size_t)im * (CIN * HW);
    const int npix = lycnt * Ww;
    for (int i = tid; i < npix; i += 256) {
        const int yy = i / Ww;
        const int x  = i - yy * Ww;
        const int y  = ly0 + yy;
        const float r0 = (ix - (float)(x * 8 + 4)) * invsoi;
        const float r1 = (iy - (float)(y * 8 + 4)) * invsoi;
        const float* fb = fb0 + y * Ww + x;
        float f[8];
#pragma unroll
        for (int c = 0; c < 8; c++) f[c] = fb[c * HW];
        float h[8];
#pragma unroll
        for (int o = 0; o < 8; o++) {
            float a = b0[o] + w0[o * 10 + 0] * r0 + w0[o * 10 + 1] * r1;
#pragma unroll
            for (int c = 0; c < 8; c++) a += w0[o * 10 + 2 + c] * f[c];
            h[o] = fmaxf(a, 0.0f);
        }
        float g[8];
#pragma unroll
        for (int o = 0; o < 8; o++) {
            float a = b1[o];
#pragma unroll
            for (int c = 0; c < 8; c++) a += w1[o * 8 + c] * h[c];
            g[o] = fmaxf(a, 0.0f);
        }
        float lg = b2;
#pragma unroll
        for (int c = 0; c < 8; c++) lg += w2[c] * g[c];
        slog[i] = lg;
    }
    __syncthreads();
    float aI = 0.0f, aS = 0.0f, aT = 0.0f;
    const float* gtn = gt + (size_t)n * (OH * OW) + (size_t)oy0 * OW;
    for (int i = tid; i < TROWS * OW; i += 256) {
        const int ry = i / OW;
        const int ox = i - ry * OW;
        const int oy = oy0 + ry;
        const float ysf = (float)oy * sy;
        const float xsf = (float)ox * sx;
        int y0 = (int)ysf, x0 = (int)xsf;
        const float wy = ysf - (float)y0;
        const float wx = xsf - (float)x0;
        int y1 = (y0 + 1 > Hh - 1) ? (Hh - 1) : (y0 + 1);
        int x1 = (x0 + 1 > Ww - 1) ? (Ww - 1) : (x0 + 1);
        int r0i = y0 - ly0, r1i = y1 - ly0;
        r0i = r0i < 0 ? 0 : (r0i > lycnt - 1 ? lycnt - 1 : r0i);
        r1i = r1i < 0 ? 0 : (r1i > lycnt - 1 ? lycnt - 1 : r1i);
        const float v00 = slog[r0i * Ww + x0];
        const float v01 = slog[r0i * Ww + x1];
        const float v10 = slog[r1i * Ww + x0];
        const float v11 = slog[r1i * Ww + x1];
        const float top = v00 + wx * (v01 - v00);
        const float bot = v10 + wx * (v11 - v10);
        const float v   = top + wy * (bot - top);
        const float s   = __fdividef(1.0f, 1.0f + __expf(-v));
        const float t   = gtn[i];
        aI += s * t; aS += s * s; aT += t;
    }
#pragma unroll
    for (int off = 32; off > 0; off >>= 1) {
        aI += __shfl_down(aI, off, 64);
        aS += __shfl_down(aS, off, 64);
        aT += __shfl_down(aT, off, 64);
    }
    const int wv = tid >> 6;
    if ((tid & 63) == 0) {
        sred[wv * 3 + 0] = aI; sred[wv * 3 + 1] = aS; sred[wv * 3 + 2] = aT;
    }
    __syncthreads();
    if (tid == 0) {
        atomicAdd(&acc[n * 3 + 0], sred[0] + sred[3] + sred[6] + sred[9]);
        atomicAdd(&acc[n * 3 + 1], sred[1] + sred[4] + sred[7] + sred[10]);
        atomicAdd(&acc[n * 3 + 2], sred[2] + sred[5] + sred[8] + sred[11]);
    }
}

__global__ __launch_bounds__(256) void dmh_fin(const float* __restrict__ acc,
                                               float* __restrict__ out)
{
    const int i = blockIdx.x * 256 + threadIdx.x;
    if (i < NINST) {
        out[i] = 1.0f - 2.0f * acc[i * 3 + 0] / (acc[i * 3 + 1] + acc[i * 3 + 2] + 1e-5f);
    }
}

extern "C" void kernel_launch(void* const* d_in, const int* in_sizes, int n_in,
                              void* d_out, int out_size, void* d_ws, size_t ws_size,
                              hipStream_t stream) {
    const float* feats  = (const float*)d_in[0];
    const float* pars   = (const float*)d_in[1];
    const float* iloc   = (const float*)d_in[2];
    const float* gt     = (const float*)d_in[3];
    const int*   iminds = (const int*)d_in[4];
    const int*   lvls   = (const int*)d_in[5];

    if (ws_size >= WS_NEEDED) {
        float* part   = (float*)d_ws;                       // 4096*3 floats
        float* logits = (float*)d_ws + LOG_OFF_FLOATS;      // 512*27200 floats
        dim3 ga(ACHUNKS, NINST);
        dmh_mlp<<<ga, 256, 0, stream>>>(feats, pars, iloc, iminds, lvls, logits);
        dim3 gb(NTILES, NINST);
        dmh_dice<<<gb, 256, 0, stream>>>(logits, gt, part);
        dmh_fin2<<<(NINST + 255) / 256, 256, 0, stream>>>(part, (float*)d_out);
    } else {
        float* acc = (float*)d_ws;
        hipMemsetAsync(acc, 0, NINST * 3 * sizeof(float), stream);
        dim3 grid(NTILES, NINST);
        dmh_fused<<<grid, 256, 0, stream>>>(feats, pars, iloc, gt, iminds, lvls, acc);
        dmh_fin<<<(NINST + 255) / 256, 256, 0, stream>>>(acc, (float*)d_out);
    }
}

// Round 4
// 422.644 us; speedup vs baseline: 1.3679x; 1.1405x over previous
//
#include <hip/hip_runtime.h>
#include <math.h>

#define NIMG 8
#define CIN 8
#define Hh 136
#define Ww 200
#define HW (Hh * Ww)
#define OH 272
#define OW 400
#define NINST 512
#define NPAR 169
#define TROWS 34
#define NTILES 8
#define LROWS 19
#define ACHUNKS 2
#define QUADS_PER_CHUNK (HW / 4 / ACHUNKS)
#define LOG_OFF_FLOATS 16384
#define WS_NEEDED ((size_t)(LOG_OFF_FLOATS + (size_t)NINST * HW) * 4)

#define PIN(x) asm volatile("" : "+v"(x))

// ---------------- Phase A: per-instance MLP -> logits (global scratch) ----------------
__global__ __launch_bounds__(256, 1) void dmh_mlp(
    const float* __restrict__ feats,
    const float* __restrict__ pars,
    const float* __restrict__ iloc,
    const int* __restrict__ iminds,
    const int* __restrict__ lvls,
    float* __restrict__ logits)
{
    const int n     = blockIdx.y;
    const int chunk = blockIdx.x;
    const int tid   = threadIdx.x;

    const float ix = iloc[2 * n + 0];
    const float iy = iloc[2 * n + 1];
    const int   im = iminds[n];
    const float invsoi = 1.0f / (float)(64 << lvls[n]);

    // 169 per-instance params -> registers, pinned so the RA cannot
    // rematerialize/reload them inside the pixel loop (R3: VGPR=40, 5x VALU).
    const float* pp = pars + n * NPAR;
    float Wf[64], w1[64], w2[8], b1[8], A0[8], Ax[8], Ay[8], b2;
#pragma unroll
    for (int o = 0; o < 8; o++) {
        const float wx0 = pp[o * 10 + 0];
        const float wy0 = pp[o * 10 + 1];
        Ax[o] = -8.0f * invsoi * wx0;
        Ay[o] = -8.0f * invsoi * wy0;
        A0[o] = pp[152 + o] + (wx0 * (ix - 4.0f) + wy0 * (iy - 4.0f)) * invsoi;
#pragma unroll
        for (int c = 0; c < 8; c++) Wf[o * 8 + c] = pp[o * 10 + 2 + c];
    }
#pragma unroll
    for (int i = 0; i < 64; i++) w1[i] = pp[80 + i];
#pragma unroll
    for (int i = 0; i < 8; i++)  w2[i] = pp[144 + i];
#pragma unroll
    for (int i = 0; i < 8; i++)  b1[i] = pp[160 + i];
    b2 = pp[168];

#pragma unroll
    for (int i = 0; i < 64; i++) PIN(Wf[i]);
#pragma unroll
    for (int i = 0; i < 64; i++) PIN(w1[i]);
#pragma unroll
    for (int i = 0; i < 8; i++) { PIN(w2[i]); PIN(b1[i]); PIN(A0[i]); PIN(Ax[i]); PIN(Ay[i]); }
    PIN(b2);

    const float* fb0 = feats + (size_t)im * (CIN * HW);
    float* lgn = logits + (size_t)n * HW;

    const int base = chunk * QUADS_PER_CHUNK;
    const int end  = base + QUADS_PER_CHUNK;
    for (int q = base + tid; q < end; q += 256) {
        const int yy = q / 50;
        const int xq = (q - yy * 50) * 4;
        const float yf = (float)yy;
        const float* fb = fb0 + yy * Ww + xq;
        float f[8][4];
#pragma unroll
        for (int c = 0; c < 8; c++) {
            const float4 t = *reinterpret_cast<const float4*>(fb + c * HW);
            f[c][0] = t.x; f[c][1] = t.y; f[c][2] = t.z; f[c][3] = t.w;
        }
        float pre[8];
#pragma unroll
        for (int o = 0; o < 8; o++) pre[o] = A0[o] + Ay[o] * yf;

        float o4[4];
#pragma unroll
        for (int p = 0; p < 4; p++) {
            const float xf = (float)(xq + p);
            float h[8];
#pragma unroll
            for (int o = 0; o < 8; o++) {
                float a = pre[o] + Ax[o] * xf;
#pragma unroll
                for (int c = 0; c < 8; c++) a += Wf[o * 8 + c] * f[c][p];
                h[o] = fmaxf(a, 0.0f);
            }
            float g[8];
#pragma unroll
            for (int o = 0; o < 8; o++) {
                float a = b1[o];
#pragma unroll
                for (int c = 0; c < 8; c++) a += w1[o * 8 + c] * h[c];
                g[o] = fmaxf(a, 0.0f);
            }
            float lg = b2;
#pragma unroll
            for (int c = 0; c < 8; c++) lg += w2[c] * g[c];
            o4[p] = lg;
        }
        *reinterpret_cast<float4*>(lgn + yy * Ww + xq) =
            make_float4(o4[0], o4[1], o4[2], o4[3]);
    }
}

// ---------------- Phase B: bilinear up + sigmoid + dice partials ----------------
__global__ __launch_bounds__(256) void dmh_dice(
    const float* __restrict__ logits,
    const float* __restrict__ gt,
    float* __restrict__ part)
{
    __shared__ float slog[LROWS * Ww];
    __shared__ float sred[12];

    const int n    = blockIdx.y;
    const int tile = blockIdx.x;
    const int tid  = threadIdx.x;

    const float sy = 135.0f / 271.0f;
    const float sx = 199.0f / 399.0f;

    const int oy0 = tile * TROWS;
    const int ly0 = (int)((float)oy0 * sy);
    int lyL = (int)((float)(oy0 + TROWS - 1) * sy) + 1;
    if (lyL > Hh - 1) lyL = Hh - 1;
    const int lycnt = lyL - ly0 + 1;

    const float* lg = logits + (size_t)n * HW + ly0 * Ww;
    const int nfl = lycnt * Ww;
    for (int i = 4 * tid; i < nfl; i += 1024) {
        *reinterpret_cast<float4*>(&slog[i]) = *reinterpret_cast<const float4*>(lg + i);
    }
    __syncthreads();

    float aI = 0.0f, aS = 0.0f, aT = 0.0f;
    const float* gtn = gt + (size_t)n * (OH * OW) + (size_t)oy0 * OW;
    for (int g4 = tid; g4 < TROWS * (OW / 4); g4 += 256) {
        const int ry = g4 / 100;
        const int gx = (g4 - ry * 100) * 4;
        const int oy = oy0 + ry;
        const float ysf = (float)oy * sy;
        const int y0 = (int)ysf;
        const float wy = ysf - (float)y0;
        const int y1 = (y0 + 1 > Hh - 1) ? (Hh - 1) : (y0 + 1);
        int r0i = y0 - ly0, r1i = y1 - ly0;
        r0i = r0i < 0 ? 0 : (r0i > lycnt - 1 ? lycnt - 1 : r0i);
        r1i = r1i < 0 ? 0 : (r1i > lycnt - 1 ? lycnt - 1 : r1i);
        const float* s0 = &slog[r0i * Ww];
        const float* s1 = &slog[r1i * Ww];

        const float4 t4 = *reinterpret_cast<const float4*>(gtn + ry * OW + gx);
        const float tv[4] = { t4.x, t4.y, t4.z, t4.w };
#pragma unroll
        for (int p = 0; p < 4; p++) {
            const int ox = gx + p;
            const float xsf = (float)ox * sx;
            const int x0 = (int)xsf;
            const float wx = xsf - (float)x0;
            const int x1 = (x0 + 1 > Ww - 1) ? (Ww - 1) : (x0 + 1);
            const float v00 = s0[x0];
            const float v01 = s0[x1];
            const float v10 = s1[x0];
            const float v11 = s1[x1];
            const float top = v00 + wx * (v01 - v00);
            const float bot = v10 + wx * (v11 - v10);
            const float v   = top + wy * (bot - top);
            const float s   = __fdividef(1.0f, 1.0f + __expf(-v));
            aI += s * tv[p];
            aS += s * s;
            aT += tv[p];
        }
    }

#pragma unroll
    for (int off = 32; off > 0; off >>= 1) {
        aI += __shfl_down(aI, off, 64);
        aS += __shfl_down(aS, off, 64);
        aT += __shfl_down(aT, off, 64);
    }
    const int wv = tid >> 6;
    if ((tid & 63) == 0) {
        sred[wv * 3 + 0] = aI;
        sred[wv * 3 + 1] = aS;
        sred[wv * 3 + 2] = aT;
    }
    __syncthreads();
    if (tid == 0) {
        float* pt = part + (size_t)(n * NTILES + tile) * 3;
        pt[0] = sred[0] + sred[3] + sred[6] + sred[9];
        pt[1] = sred[1] + sred[4] + sred[7] + sred[10];
        pt[2] = sred[2] + sred[5] + sred[8] + sred[11];
    }
}

__global__ __launch_bounds__(256) void dmh_fin2(const float* __restrict__ part,
                                                float* __restrict__ out)
{
    const int i = blockIdx.x * 256 + threadIdx.x;
    if (i < NINST) {
        float I = 0.0f, S = 0.0f, T = 0.0f;
#pragma unroll
        for (int t = 0; t < NTILES; t++) {
            const float* pt = part + (size_t)(i * NTILES + t) * 3;
            I += pt[0]; S += pt[1]; T += pt[2];
        }
        out[i] = 1.0f - 2.0f * I / (S + T + 1e-5f);
    }
}

// ---------------- Fallback fused path (R1, known-good) if ws too small ----------------
__global__ __launch_bounds__(256) void dmh_fused(
    const float* __restrict__ feats,
    const float* __restrict__ pars,
    const float* __restrict__ iloc,
    const float* __restrict__ gt,
    const int* __restrict__ iminds,
    const int* __restrict__ lvls,
    float* __restrict__ acc)
{
    __shared__ float slog[LROWS * Ww];
    __shared__ float sred[12];
    const int n = blockIdx.y, tile = blockIdx.x, tid = threadIdx.x;
    const float* pp = pars + n * NPAR;
    float w0[80], w1[64], w2[8], b0[8], b1[8], b2;
#pragma unroll
    for (int i = 0; i < 80; i++) w0[i] = pp[i];
#pragma unroll
    for (int i = 0; i < 64; i++) w1[i] = pp[80 + i];
#pragma unroll
    for (int i = 0; i < 8; i++)  w2[i] = pp[144 + i];
#pragma unroll
    for (int i = 0; i < 8; i++)  b0[i] = pp[152 + i];
#pragma unroll
    for (int i = 0; i < 8; i++)  b1[i] = pp[160 + i];
    b2 = pp[168];
    const float ix = iloc[2 * n + 0], iy = iloc[2 * n + 1];
    const int im = iminds[n];
    const float invsoi = 1.0f / (float)(64 << lvls[n]);
    const float sy = 135.0f / 271.0f, sx = 199.0f / 399.0f;
    const int oy0 = tile * TROWS;
    const int ly0 = (int)((float)oy0 * sy);
    int lyL = (int)((float)(oy0 + TROWS - 1) * sy) + 1;
    if (lyL > Hh - 1) lyL = Hh - 1;
    const int lycnt = lyL - ly0 + 1;
    const float* fb0 = feats + (size_t)im * (CIN * HW);
    const int npix = lycnt * Ww;
    for (int i = tid; i < npix; i += 256) {
        const int yy = i / Ww;
        const int x  = i - yy * Ww;
        const int y  = ly0 + yy;
        const float r0 = (ix - (float)(x * 8 + 4)) * invsoi;
        const float r1 = (iy - (float)(y * 8 + 4)) * invsoi;
        const float* fb = fb0 + y * Ww + x;
        float f[8];
#pragma unroll
        for (int c = 0; c < 8; c++) f[c] = fb[c * HW];
        float h[8];
#pragma unroll
        for (int o = 0; o < 8; o++) {
            float a = b0[o] + w0[o * 10 + 0] * r0 + w0[o * 10 + 1] * r1;
#pragma unroll
            for (int c = 0; c < 8; c++) a += w0[o * 10 + 2 + c] * f[c];
            h[o] = fmaxf(a, 0.0f);
        }
        float g[8];
#pragma unroll
        for (int o = 0; o < 8; o++) {
            float a = b1[o];
#pragma unroll
            for (int c = 0; c < 8; c++) a += w1[o * 8 + c] * h[c];
            g[o] = fmaxf(a, 0.0f);
        }
        float lg = b2;
#pragma unroll
        for (int c = 0; c < 8; c++) lg += w2[c] * g[c];
        slog[i] = lg;
    }
    __syncthreads();
    float aI = 0.0f, aS = 0.0f, aT = 0.0f;
    const float* gtn = gt + (size_t)n * (OH * OW) + (size_t)oy0 * OW;
    for (int i = tid; i < TROWS * OW; i += 256) {
        const int ry = i / OW;
        const int ox = i - ry * OW;
        const int oy = oy0 + ry;
        const float ysf = (float)oy * sy;
        const float xsf = (float)ox * sx;
        int y0 = (int)ysf, x0 = (int)xsf;
        const float wy = ysf - (float)y0;
        const float wx = xsf - (float)x0;
        int y1 = (y0 + 1 > Hh - 1) ? (Hh - 1) : (y0 + 1);
        int x1 = (x0 + 1 > Ww - 1) ? (Ww - 1) : (x0 + 1);
        int r0i = y0 - ly0, r1i = y1 - ly0;
        r0i = r0i < 0 ? 0 : (r0i > lycnt - 1 ? lycnt - 1 : r0i);
        r1i = r1i < 0 ? 0 : (r1i > lycnt - 1 ? lycnt - 1 : r1i);
        const float v00 = slog[r0i * Ww + x0];
        const float v01 = slog[r0i * Ww + x1];
        const float v10 = slog[r1i * Ww + x0];
        const float v11 = slog[r1i * Ww + x1];
        const float top = v00 + wx * (v01 - v00);
        const float bot = v10 + wx * (v11 - v10);
        const float v   = top + wy * (bot - top);
        const float s   = __fdividef(1.0f, 1.0f + __expf(-v));
        const float t   = gtn[i];
        aI += s * t; aS += s * s; aT += t;
    }
#pragma unroll
    for (int off = 32; off > 0; off >>= 1) {
        aI += __shfl_down(aI, off, 64);
        aS += __shfl_down(aS, off, 64);
        aT += __shfl_down(aT, off, 64);
    }
    const int wv = tid >> 6;
    if ((tid & 63) == 0) {
        sred[wv * 3 + 0] = aI; sred[wv * 3 + 1] = aS; sred[wv * 3 + 2] = aT;
    }
    __syncthreads();
    if (tid == 0) {
        atomicAdd(&acc[n * 3 + 0], sred[0] + sred[3] + sred[6] + sred[9]);
        atomicAdd(&acc[n * 3 + 1], sred[1] + sred[4] + sred[7] + sred[10]);
        atomicAdd(&acc[n * 3 + 2], sred[2] + sred[5] + sred[8] + sred[11]);
    }
}

__global__ __launch_bounds__(256) void dmh_fin(const float* __restrict__ acc,
                                               float* __restrict__ out)
{
    const int i = blockIdx.x * 256 + threadIdx.x;
    if (i < NINST) {
        out[i] = 1.0f - 2.0f * acc[i * 3 + 0] / (acc[i * 3 + 1] + acc[i * 3 + 2] + 1e-5f);
    }
}

extern "C" void kernel_launch(void* const* d_in, const int* in_sizes, int n_in,
                              void* d_out, int out_size, void* d_ws, size_t ws_size,
                              hipStream_t stream) {
    const float* feats  = (const float*)d_in[0];
    const float* pars   = (const float*)d_in[1];
    const float* iloc   = (const float*)d_in[2];
    const float* gt     = (const float*)d_in[3];
    const int*   iminds = (const int*)d_in[4];
    const int*   lvls   = (const int*)d_in[5];

    if (ws_size >= WS_NEEDED) {
        float* part   = (float*)d_ws;                       // 4096*3 floats
        float* logits = (float*)d_ws + LOG_OFF_FLOATS;      // 512*27200 floats
        dim3 ga(ACHUNKS, NINST);
        dmh_mlp<<<ga, 256, 0, stream>>>(feats, pars, iloc, iminds, lvls, logits);
        dim3 gb(NTILES, NINST);
        dmh_dice<<<gb, 256, 0, stream>>>(logits, gt, part);
        dmh_fin2<<<(NINST + 255) / 256, 256, 0, stream>>>(part, (float*)d_out);
    } else {
        float* acc = (float*)d_ws;
        hipMemsetAsync(acc, 0, NINST * 3 * sizeof(float), stream);
        dim3 grid(NTILES, NINST);
        dmh_fused<<<grid, 256, 0, stream>>>(feats, pars, iloc, gt, iminds, lvls, acc);
        dmh_fin<<<(NINST + 255) / 256, 256, 0, stream>>>(acc, (float*)d_out);
    }
}